// Round 4
// baseline (1016.553 us; speedup 1.0000x reference)
//
#include <hip/hip_runtime.h>
#include <hip/hip_bf16.h>

#define S_ 64
#define P_ 2048
#define C_ 32
#define A_ 2048
#define D_ 128
#define E_ 64

#define PCH   256            // pixels per logits chunk
#define NCH   (P_ / PCH)     // 8
#define NSLOT 2              // agent-group slots per (scene,chunk)
#define PPC   128            // pixels per pool chunk
#define NPCH  (P_ / PPC)     // 16

// ---------------------------------------------------------------------------
// att2[a,e] = de[a,:] @ W_df + b_df
// ---------------------------------------------------------------------------
__global__ __launch_bounds__(256) void att2_kernel(
    const float* __restrict__ de, const float* __restrict__ Wdf,
    const float* __restrict__ bdf, float* __restrict__ att2) {
  __shared__ float4 Wl[128 * 16];
  __shared__ float4 bl[16];
  __shared__ float  dl[16 * 128];
  const int tid = threadIdx.x;

  const float4* W4 = (const float4*)Wdf;
#pragma unroll
  for (int i = 0; i < 8; ++i) Wl[tid + i * 256] = W4[tid + i * 256];
  if (tid < 16) bl[tid] = ((const float4*)bdf)[tid];
  const long base = (long)blockIdx.x * (16 * 128);
#pragma unroll
  for (int i = 0; i < 8; ++i) dl[tid + i * 256] = de[base + tid + i * 256];
  __syncthreads();

  const int r = tid >> 4, e4 = tid & 15;
  float4 acc = bl[e4];
#pragma unroll 4
  for (int d = 0; d < 128; ++d) {
    const float  g = dl[r * 128 + d];
    const float4 w = Wl[d * 16 + e4];
    acc.x = fmaf(g, w.x, acc.x);
    acc.y = fmaf(g, w.y, acc.y);
    acc.z = fmaf(g, w.z, acc.z);
    acc.w = fmaf(g, w.w, acc.w);
  }
  ((float4*)att2)[((long)blockIdx.x * 16 + r) * 16 + e4] = acc;
}

// ---------------------------------------------------------------------------
// Bucket agents by scene.
// ---------------------------------------------------------------------------
__global__ void scatter_kernel(const int* __restrict__ sidx,
                               int* __restrict__ counts, int* __restrict__ lists) {
  const int a = blockIdx.x * 256 + threadIdx.x;
  const int s = sidx[a];
  const int pos = atomicAdd(&counts[s], 1);
  lists[s * A_ + pos] = a;
}

// ---------------------------------------------------------------------------
// logits[a,p] = sum_e relu(att1[s,p,e] + att2[a,e]) * w_fc[e]
// Block = (scene, chunk, slot). Thread owns pixel p0+tid: gs row in regs,
// att1 row in regs. Agents staged 32 at a time (2 barriers per group);
// slots stride the groups so 2 blocks share each (scene,chunk).
// ---------------------------------------------------------------------------
__global__ __launch_bounds__(256, 4) void logits_kernel(
    const float* __restrict__ gs, const float* __restrict__ Wsn,
    const float* __restrict__ bsn, const float* __restrict__ wfc,
    const float* __restrict__ att2, const int* __restrict__ counts,
    const int* __restrict__ lists, float* __restrict__ logits) {
  const int b    = blockIdx.x;
  const int slot = b & (NSLOT - 1);
  const int ch   = (b >> 1) & (NCH - 1);
  const int s    = b >> 4;               // NSLOT*NCH = 16
  const int p0   = ch * PCH;
  const int tid  = threadIdx.x;

  __shared__ float4 Wl[32 * 16];   // W_sn [c][e4]  (8 KB)
  __shared__ float4 wfl[16];
  __shared__ float4 a2l[32][16];   // att2 rows of current group (2 KB)
  __shared__ int    aid[32];

  const float4* W4 = (const float4*)Wsn;
  Wl[tid]       = W4[tid];
  Wl[tid + 256] = W4[tid + 256];
  if (tid < 16) wfl[tid] = ((const float4*)wfc)[tid];

  // gs row for pixel p0+tid -> registers (16B/lane; L1 serves full lines)
  const float4* g4 = (const float4*)(gs + ((long)s * P_ + p0 + tid) * C_);
  float4 g[8];
#pragma unroll
  for (int i = 0; i < 8; ++i) g[i] = g4[i];

  __syncthreads();

  // att1 row in registers
  const float4* b4 = (const float4*)bsn;
  float4 a1[16];
#pragma unroll
  for (int e4 = 0; e4 < 16; ++e4) a1[e4] = b4[e4];
#pragma unroll
  for (int i = 0; i < 8; ++i) {
    const float gc[4] = {g[i].x, g[i].y, g[i].z, g[i].w};
#pragma unroll
    for (int q = 0; q < 4; ++q) {
      const float gv = gc[q];
      const int   c  = i * 4 + q;
#pragma unroll
      for (int e4 = 0; e4 < 16; ++e4) {
        const float4 w = Wl[c * 16 + e4];
        a1[e4].x = fmaf(gv, w.x, a1[e4].x);
        a1[e4].y = fmaf(gv, w.y, a1[e4].y);
        a1[e4].z = fmaf(gv, w.z, a1[e4].z);
        a1[e4].w = fmaf(gv, w.w, a1[e4].w);
      }
    }
  }

  const int n_s = counts[s];
  for (int g0 = slot * 32; g0 < n_s; g0 += NSLOT * 32) {
    const int m = min(32, n_s - g0);
    __syncthreads();                      // prev-group a2l reads done
    if (tid < m) aid[tid] = lists[s * A_ + g0 + tid];
    __syncthreads();
#pragma unroll
    for (int k = 0; k < 2; ++k) {
      const int idx = tid + k * 256;      // 0..511
      const int j = idx >> 4, e4 = idx & 15;
      if (j < m) a2l[j][e4] = ((const float4*)att2)[aid[j] * 16 + e4];
    }
    __syncthreads();
    for (int j = 0; j < m; ++j) {
      float acc = 0.f;
#pragma unroll
      for (int e4 = 0; e4 < 16; ++e4) {
        const float4 t = a2l[j][e4];
        const float4 w = wfl[e4];
        acc = fmaf(fmaxf(a1[e4].x + t.x, 0.f), w.x, acc);
        acc = fmaf(fmaxf(a1[e4].y + t.y, 0.f), w.y, acc);
        acc = fmaf(fmaxf(a1[e4].z + t.z, 0.f), w.z, acc);
        acc = fmaf(fmaxf(a1[e4].w + t.w, 0.f), w.w, acc);
      }
      logits[(long)aid[j] * P_ + p0 + tid] = acc;
    }
  }
}

// ---------------------------------------------------------------------------
// Per-agent softmax stats: stats[a] = (max, 1/sum(exp(l-max)))
// ---------------------------------------------------------------------------
__global__ __launch_bounds__(256) void stats_kernel(
    const float* __restrict__ logits, float2* __restrict__ stats) {
  const int a = blockIdx.x, tid = threadIdx.x;
  __shared__ float red[8];
  const float4* l4 = (const float4*)(logits + (long)a * P_);
  const float4 v0 = l4[tid], v1 = l4[tid + 256];
  float m = fmaxf(fmaxf(fmaxf(v0.x, v0.y), fmaxf(v0.z, v0.w)),
                  fmaxf(fmaxf(v1.x, v1.y), fmaxf(v1.z, v1.w)));
#pragma unroll
  for (int off = 1; off < 64; off <<= 1) m = fmaxf(m, __shfl_xor(m, off));
  if ((tid & 63) == 0) red[tid >> 6] = m;
  __syncthreads();
  m = fmaxf(fmaxf(red[0], red[1]), fmaxf(red[2], red[3]));

  float sum = __expf(v0.x - m) + __expf(v0.y - m) + __expf(v0.z - m) + __expf(v0.w - m)
            + __expf(v1.x - m) + __expf(v1.y - m) + __expf(v1.z - m) + __expf(v1.w - m);
#pragma unroll
  for (int off = 1; off < 64; off <<= 1) sum += __shfl_xor(sum, off);
  if ((tid & 63) == 0) red[4 + (tid >> 6)] = sum;
  __syncthreads();
  if (tid == 0) {
    const float Z = red[4] + red[5] + red[6] + red[7];
    stats[a] = make_float2(m, 1.0f / Z);
  }
}

// ---------------------------------------------------------------------------
// out[a,c] += sum_{p in chunk} alpha[a,p] * gs[s,p,c]
// Block = (scene, 128-px chunk). gs chunk + alpha(32 agents) in LDS.
// One thread per (agent-slot j=tid>>3, channel-quad c4=tid&7); inner loop
// is barrier-free LDS broadcasts. 2 barriers per 32-agent group.
// ---------------------------------------------------------------------------
__global__ __launch_bounds__(256) void pool_kernel(
    const float* __restrict__ logits, const float2* __restrict__ stats,
    const int* __restrict__ counts, const int* __restrict__ lists,
    const float* __restrict__ gs, float* __restrict__ out) {
  const int s   = blockIdx.x >> 4;
  const int p0  = (blockIdx.x & (NPCH - 1)) * PPC;
  const int tid = threadIdx.x;
  const int j   = tid >> 3;              // agent slot 0..31
  const int c4  = tid & 7;               // channel quad

  __shared__ float4 gsl[PPC][8];         // 16 KB, linear copy of gs chunk
  __shared__ float  alpha_l[32][PPC];    // 16 KB
  __shared__ float2 sm[32];
  __shared__ int    aid[32];

  const float4* g4 = (const float4*)(gs + ((long)s * P_ + p0) * C_);
  float4* gl = (float4*)gsl;
#pragma unroll
  for (int k = 0; k < 4; ++k) gl[tid + k * 256] = g4[tid + k * 256];

  const float4* l4 = (const float4*)logits;
  const int n_s = counts[s];

  for (int g0 = 0; g0 < n_s; g0 += 32) {
    const int m = min(32, n_s - g0);
    __syncthreads();                     // prev-group LDS reads done (+gsl ready)
    if (tid < m) {
      const int a = lists[s * A_ + g0 + tid];
      aid[tid] = a;
      sm[tid]  = stats[a];
    }
    __syncthreads();

    // stage alpha rows: 32 agents x 128 px = 1024 float4
#pragma unroll
    for (int k = 0; k < 4; ++k) {
      const int idx = tid + k * 256;     // 0..1023
      const int jj = idx >> 5, p4 = idx & 31;
      if (jj < m) {
        const float2 ms = sm[jj];
        const float4 v  = l4[(long)aid[jj] * (P_ / 4) + (p0 >> 2) + p4];
        float4 al;
        al.x = __expf(v.x - ms.x) * ms.y;
        al.y = __expf(v.y - ms.x) * ms.y;
        al.z = __expf(v.z - ms.x) * ms.y;
        al.w = __expf(v.w - ms.x) * ms.y;
        ((float4*)alpha_l[jj])[p4] = al;
      }
    }
    __syncthreads();

    if (j < m) {
      float4 acc = make_float4(0.f, 0.f, 0.f, 0.f);
#pragma unroll 4
      for (int p = 0; p < PPC; ++p) {
        const float  w = alpha_l[j][p];
        const float4 v = gsl[p][c4];
        acc.x = fmaf(w, v.x, acc.x);
        acc.y = fmaf(w, v.y, acc.y);
        acc.z = fmaf(w, v.z, acc.z);
        acc.w = fmaf(w, v.w, acc.w);
      }
      float* op = out + (long)aid[j] * C_ + c4 * 4;
      atomicAdd(op,     acc.x);
      atomicAdd(op + 1, acc.y);
      atomicAdd(op + 2, acc.z);
      atomicAdd(op + 3, acc.w);
    }
  }
}

// ---------------------------------------------------------------------------
extern "C" void kernel_launch(void* const* d_in, const int* in_sizes, int n_in,
                              void* d_out, int out_size, void* d_ws, size_t ws_size,
                              hipStream_t stream) {
  const float* gs   = (const float*)d_in[0];  // [S,P,C]
  const int*   sidx = (const int*)  d_in[1];  // [A]
  const float* de   = (const float*)d_in[2];  // [A,D]
  const float* Wsn  = (const float*)d_in[3];  // [C,E]
  const float* bsn  = (const float*)d_in[4];  // [E]
  const float* Wdf  = (const float*)d_in[5];  // [D,E]
  const float* bdf  = (const float*)d_in[6];  // [E]
  const float* wfc  = (const float*)d_in[7];  // [E]
  // d_in[8] = b_fc: constant shift, softmax-invariant — unused.
  float* out = (float*)d_out;

  float*  att2   = (float*)d_ws;                       // A*E   = 0.5 MB
  float*  logits = att2 + (long)A_ * E_;               // A*P   = 16 MB
  float2* stats  = (float2*)(logits + (long)A_ * P_);  // A     = 16 KB
  int*    counts = (int*)(stats + A_);                 // 64
  int*    lists  = counts + 64;                        // S*A   = 0.5 MB

  hipMemsetAsync(counts, 0, 64 * sizeof(int), stream);
  hipMemsetAsync(out, 0, (size_t)out_size * sizeof(float), stream);

  att2_kernel   <<<A_ / 16,           256, 0, stream>>>(de, Wdf, bdf, att2);
  scatter_kernel<<<A_ / 256,          256, 0, stream>>>(sidx, counts, lists);
  logits_kernel <<<S_ * NCH * NSLOT,  256, 0, stream>>>(gs, Wsn, bsn, wfc, att2,
                                                        counts, lists, logits);
  stats_kernel  <<<A_,                256, 0, stream>>>(logits, stats);
  pool_kernel   <<<S_ * NPCH,         256, 0, stream>>>(logits, stats, counts,
                                                        lists, gs, out);
}

// Round 5
// 258.034 us; speedup vs baseline: 3.9396x; 3.9396x over previous
//
#include <hip/hip_runtime.h>
#include <hip/hip_bf16.h>

#define S_ 64
#define P_ 2048
#define C_ 32
#define A_ 2048
#define D_ 128
#define E_ 64

#define PCH   256            // pixels per logits chunk
#define NCH   (P_ / PCH)     // 8
#define NSLOT 2              // agent-group slots per (scene,chunk)
#define PPC   128            // pixels per pool chunk
#define NPCH  (P_ / PPC)     // 16

// ---------------------------------------------------------------------------
// att2[a,e] = de[a,:] @ W_df + b_df
// ---------------------------------------------------------------------------
__global__ __launch_bounds__(256) void att2_kernel(
    const float* __restrict__ de, const float* __restrict__ Wdf,
    const float* __restrict__ bdf, float* __restrict__ att2) {
  __shared__ float4 Wl[128 * 16];
  __shared__ float4 bl[16];
  __shared__ float  dl[16 * 128];
  const int tid = threadIdx.x;

  const float4* W4 = (const float4*)Wdf;
#pragma unroll
  for (int i = 0; i < 8; ++i) Wl[tid + i * 256] = W4[tid + i * 256];
  if (tid < 16) bl[tid] = ((const float4*)bdf)[tid];
  const long base = (long)blockIdx.x * (16 * 128);
#pragma unroll
  for (int i = 0; i < 8; ++i) dl[tid + i * 256] = de[base + tid + i * 256];
  __syncthreads();

  const int r = tid >> 4, e4 = tid & 15;
  float4 acc = bl[e4];
#pragma unroll 4
  for (int d = 0; d < 128; ++d) {
    const float  g = dl[r * 128 + d];
    const float4 w = Wl[d * 16 + e4];
    acc.x = fmaf(g, w.x, acc.x);
    acc.y = fmaf(g, w.y, acc.y);
    acc.z = fmaf(g, w.z, acc.z);
    acc.w = fmaf(g, w.w, acc.w);
  }
  ((float4*)att2)[((long)blockIdx.x * 16 + r) * 16 + e4] = acc;
}

// ---------------------------------------------------------------------------
// Bucket agents by scene.
// ---------------------------------------------------------------------------
__global__ void scatter_kernel(const int* __restrict__ sidx,
                               int* __restrict__ counts, int* __restrict__ lists) {
  const int a = blockIdx.x * 256 + threadIdx.x;
  const int s = sidx[a];
  const int pos = atomicAdd(&counts[s], 1);
  lists[s * A_ + pos] = a;
}

// ---------------------------------------------------------------------------
// logits[a,p] = sum_e relu(att1[s,p,e] + att2[a,e]) * w_fc[e]
// Block = (scene, chunk, slot). Thread owns pixel p0+tid: gs row in regs,
// att1 row in regs (64 VGPR live state — NO min-occupancy launch bound,
// R4's (256,4) capped VGPR at 64 and spilled ~2.1 GB to scratch).
// ---------------------------------------------------------------------------
__global__ __launch_bounds__(256) void logits_kernel(
    const float* __restrict__ gs, const float* __restrict__ Wsn,
    const float* __restrict__ bsn, const float* __restrict__ wfc,
    const float* __restrict__ att2, const int* __restrict__ counts,
    const int* __restrict__ lists, float* __restrict__ logits) {
  const int b    = blockIdx.x;
  const int slot = b & (NSLOT - 1);
  const int ch   = (b >> 1) & (NCH - 1);
  const int s    = b >> 4;               // NSLOT*NCH = 16
  const int p0   = ch * PCH;
  const int tid  = threadIdx.x;

  __shared__ float4 Wl[32 * 16];   // W_sn [c][e4]  (8 KB)
  __shared__ float4 wfl[16];
  __shared__ float4 a2l[32][16];   // att2 rows of current group (2 KB)
  __shared__ int    aid[32];

  const float4* W4 = (const float4*)Wsn;
  Wl[tid]       = W4[tid];
  Wl[tid + 256] = W4[tid + 256];
  if (tid < 16) wfl[tid] = ((const float4*)wfc)[tid];

  // gs row for pixel p0+tid -> registers (16B/lane; L1 serves full lines)
  const float4* g4 = (const float4*)(gs + ((long)s * P_ + p0 + tid) * C_);
  float4 g[8];
#pragma unroll
  for (int i = 0; i < 8; ++i) g[i] = g4[i];

  __syncthreads();

  // att1 row in registers
  const float4* b4 = (const float4*)bsn;
  float4 a1[16];
#pragma unroll
  for (int e4 = 0; e4 < 16; ++e4) a1[e4] = b4[e4];
#pragma unroll
  for (int i = 0; i < 8; ++i) {
    const float gc[4] = {g[i].x, g[i].y, g[i].z, g[i].w};
#pragma unroll
    for (int q = 0; q < 4; ++q) {
      const float gv = gc[q];
      const int   c  = i * 4 + q;
#pragma unroll
      for (int e4 = 0; e4 < 16; ++e4) {
        const float4 w = Wl[c * 16 + e4];
        a1[e4].x = fmaf(gv, w.x, a1[e4].x);
        a1[e4].y = fmaf(gv, w.y, a1[e4].y);
        a1[e4].z = fmaf(gv, w.z, a1[e4].z);
        a1[e4].w = fmaf(gv, w.w, a1[e4].w);
      }
    }
  }

  const int n_s = counts[s];
  for (int g0 = slot * 32; g0 < n_s; g0 += NSLOT * 32) {
    const int m = min(32, n_s - g0);
    __syncthreads();                      // prev-group a2l reads done
    if (tid < m) aid[tid] = lists[s * A_ + g0 + tid];
    __syncthreads();
#pragma unroll
    for (int k = 0; k < 2; ++k) {
      const int idx = tid + k * 256;      // 0..511
      const int j = idx >> 4, e4 = idx & 15;
      if (j < m) a2l[j][e4] = ((const float4*)att2)[aid[j] * 16 + e4];
    }
    __syncthreads();
    for (int j = 0; j < m; ++j) {
      float acc = 0.f;
#pragma unroll
      for (int e4 = 0; e4 < 16; ++e4) {
        const float4 t = a2l[j][e4];
        const float4 w = wfl[e4];
        acc = fmaf(fmaxf(a1[e4].x + t.x, 0.f), w.x, acc);
        acc = fmaf(fmaxf(a1[e4].y + t.y, 0.f), w.y, acc);
        acc = fmaf(fmaxf(a1[e4].z + t.z, 0.f), w.z, acc);
        acc = fmaf(fmaxf(a1[e4].w + t.w, 0.f), w.w, acc);
      }
      logits[(long)aid[j] * P_ + p0 + tid] = acc;
    }
  }
}

// ---------------------------------------------------------------------------
// Per-agent softmax stats: stats[a] = (max, 1/sum(exp(l-max)))
// ---------------------------------------------------------------------------
__global__ __launch_bounds__(256) void stats_kernel(
    const float* __restrict__ logits, float2* __restrict__ stats) {
  const int a = blockIdx.x, tid = threadIdx.x;
  __shared__ float red[8];
  const float4* l4 = (const float4*)(logits + (long)a * P_);
  const float4 v0 = l4[tid], v1 = l4[tid + 256];
  float m = fmaxf(fmaxf(fmaxf(v0.x, v0.y), fmaxf(v0.z, v0.w)),
                  fmaxf(fmaxf(v1.x, v1.y), fmaxf(v1.z, v1.w)));
#pragma unroll
  for (int off = 1; off < 64; off <<= 1) m = fmaxf(m, __shfl_xor(m, off));
  if ((tid & 63) == 0) red[tid >> 6] = m;
  __syncthreads();
  m = fmaxf(fmaxf(red[0], red[1]), fmaxf(red[2], red[3]));

  float sum = __expf(v0.x - m) + __expf(v0.y - m) + __expf(v0.z - m) + __expf(v0.w - m)
            + __expf(v1.x - m) + __expf(v1.y - m) + __expf(v1.z - m) + __expf(v1.w - m);
#pragma unroll
  for (int off = 1; off < 64; off <<= 1) sum += __shfl_xor(sum, off);
  if ((tid & 63) == 0) red[4 + (tid >> 6)] = sum;
  __syncthreads();
  if (tid == 0) {
    const float Z = red[4] + red[5] + red[6] + red[7];
    stats[a] = make_float2(m, 1.0f / Z);
  }
}

// ---------------------------------------------------------------------------
// out[a,c] += sum_{p in chunk} alpha[a,p] * gs[s,p,c]
// Block = (scene, 128-px chunk). gs chunk + alpha(32 agents) in LDS.
// One thread per (agent-slot j=tid>>3, channel-quad c4=tid&7); inner loop
// is barrier-free LDS broadcasts. 2 barriers per 32-agent group.
// ---------------------------------------------------------------------------
__global__ __launch_bounds__(256) void pool_kernel(
    const float* __restrict__ logits, const float2* __restrict__ stats,
    const int* __restrict__ counts, const int* __restrict__ lists,
    const float* __restrict__ gs, float* __restrict__ out) {
  const int s   = blockIdx.x >> 4;
  const int p0  = (blockIdx.x & (NPCH - 1)) * PPC;
  const int tid = threadIdx.x;
  const int j   = tid >> 3;              // agent slot 0..31
  const int c4  = tid & 7;               // channel quad

  __shared__ float4 gsl[PPC][8];         // 16 KB, linear copy of gs chunk
  __shared__ float  alpha_l[32][PPC];    // 16 KB
  __shared__ float2 sm[32];
  __shared__ int    aid[32];

  const float4* g4 = (const float4*)(gs + ((long)s * P_ + p0) * C_);
  float4* gl = (float4*)gsl;
#pragma unroll
  for (int k = 0; k < 4; ++k) gl[tid + k * 256] = g4[tid + k * 256];

  const float4* l4 = (const float4*)logits;
  const int n_s = counts[s];

  for (int g0 = 0; g0 < n_s; g0 += 32) {
    const int m = min(32, n_s - g0);
    __syncthreads();                     // prev-group LDS reads done (+gsl ready)
    if (tid < m) {
      const int a = lists[s * A_ + g0 + tid];
      aid[tid] = a;
      sm[tid]  = stats[a];
    }
    __syncthreads();

    // stage alpha rows: 32 agents x 128 px = 1024 float4
#pragma unroll
    for (int k = 0; k < 4; ++k) {
      const int idx = tid + k * 256;     // 0..1023
      const int jj = idx >> 5, p4 = idx & 31;
      if (jj < m) {
        const float2 ms = sm[jj];
        const float4 v  = l4[(long)aid[jj] * (P_ / 4) + (p0 >> 2) + p4];
        float4 al;
        al.x = __expf(v.x - ms.x) * ms.y;
        al.y = __expf(v.y - ms.x) * ms.y;
        al.z = __expf(v.z - ms.x) * ms.y;
        al.w = __expf(v.w - ms.x) * ms.y;
        ((float4*)alpha_l[jj])[p4] = al;
      }
    }
    __syncthreads();

    if (j < m) {
      float4 acc = make_float4(0.f, 0.f, 0.f, 0.f);
#pragma unroll 4
      for (int p = 0; p < PPC; ++p) {
        const float  w = alpha_l[j][p];
        const float4 v = gsl[p][c4];
        acc.x = fmaf(w, v.x, acc.x);
        acc.y = fmaf(w, v.y, acc.y);
        acc.z = fmaf(w, v.z, acc.z);
        acc.w = fmaf(w, v.w, acc.w);
      }
      float* op = out + (long)aid[j] * C_ + c4 * 4;
      atomicAdd(op,     acc.x);
      atomicAdd(op + 1, acc.y);
      atomicAdd(op + 2, acc.z);
      atomicAdd(op + 3, acc.w);
    }
  }
}

// ---------------------------------------------------------------------------
extern "C" void kernel_launch(void* const* d_in, const int* in_sizes, int n_in,
                              void* d_out, int out_size, void* d_ws, size_t ws_size,
                              hipStream_t stream) {
  const float* gs   = (const float*)d_in[0];  // [S,P,C]
  const int*   sidx = (const int*)  d_in[1];  // [A]
  const float* de   = (const float*)d_in[2];  // [A,D]
  const float* Wsn  = (const float*)d_in[3];  // [C,E]
  const float* bsn  = (const float*)d_in[4];  // [E]
  const float* Wdf  = (const float*)d_in[5];  // [D,E]
  const float* bdf  = (const float*)d_in[6];  // [E]
  const float* wfc  = (const float*)d_in[7];  // [E]
  // d_in[8] = b_fc: constant shift, softmax-invariant — unused.
  float* out = (float*)d_out;

  float*  att2   = (float*)d_ws;                       // A*E   = 0.5 MB
  float*  logits = att2 + (long)A_ * E_;               // A*P   = 16 MB
  float2* stats  = (float2*)(logits + (long)A_ * P_);  // A     = 16 KB
  int*    counts = (int*)(stats + A_);                 // 64
  int*    lists  = counts + 64;                        // S*A   = 0.5 MB

  hipMemsetAsync(counts, 0, 64 * sizeof(int), stream);
  hipMemsetAsync(out, 0, (size_t)out_size * sizeof(float), stream);

  att2_kernel   <<<A_ / 16,           256, 0, stream>>>(de, Wdf, bdf, att2);
  scatter_kernel<<<A_ / 256,          256, 0, stream>>>(sidx, counts, lists);
  logits_kernel <<<S_ * NCH * NSLOT,  256, 0, stream>>>(gs, Wsn, bsn, wfc, att2,
                                                        counts, lists, logits);
  stats_kernel  <<<A_,                256, 0, stream>>>(logits, stats);
  pool_kernel   <<<S_ * NPCH,         256, 0, stream>>>(logits, stats, counts,
                                                        lists, gs, out);
}

// Round 6
// 158.722 us; speedup vs baseline: 6.4046x; 1.6257x over previous
//
#include <hip/hip_runtime.h>
#include <hip/hip_bf16.h>

#define S_ 64
#define P_ 2048
#define C_ 32
#define A_ 2048
#define D_ 128
#define E_ 64

#define LPX   64             // pixels per logits block
#define NLCH  (P_ / LPX)     // 32 chunks
#define PPC   128            // pixels per pool chunk
#define NPCH  (P_ / PPC)     // 16

// ---------------------------------------------------------------------------
// att2[a,e] = de[a,:] @ W_df + b_df
// ---------------------------------------------------------------------------
__global__ __launch_bounds__(256) void att2_kernel(
    const float* __restrict__ de, const float* __restrict__ Wdf,
    const float* __restrict__ bdf, float* __restrict__ att2) {
  __shared__ float4 Wl[128 * 16];
  __shared__ float4 bl[16];
  __shared__ float  dl[16 * 128];
  const int tid = threadIdx.x;

  const float4* W4 = (const float4*)Wdf;
#pragma unroll
  for (int i = 0; i < 8; ++i) Wl[tid + i * 256] = W4[tid + i * 256];
  if (tid < 16) bl[tid] = ((const float4*)bdf)[tid];
  const long base = (long)blockIdx.x * (16 * 128);
#pragma unroll
  for (int i = 0; i < 8; ++i) dl[tid + i * 256] = de[base + tid + i * 256];
  __syncthreads();

  const int r = tid >> 4, e4 = tid & 15;
  float4 acc = bl[e4];
#pragma unroll 4
  for (int d = 0; d < 128; ++d) {
    const float  g = dl[r * 128 + d];
    const float4 w = Wl[d * 16 + e4];
    acc.x = fmaf(g, w.x, acc.x);
    acc.y = fmaf(g, w.y, acc.y);
    acc.z = fmaf(g, w.z, acc.z);
    acc.w = fmaf(g, w.w, acc.w);
  }
  ((float4*)att2)[((long)blockIdx.x * 16 + r) * 16 + e4] = acc;
}

// ---------------------------------------------------------------------------
// Bucket agents by scene.
// ---------------------------------------------------------------------------
__global__ void scatter_kernel(const int* __restrict__ sidx,
                               int* __restrict__ counts, int* __restrict__ lists) {
  const int a = blockIdx.x * 256 + threadIdx.x;
  const int s = sidx[a];
  const int pos = atomicAdd(&counts[s], 1);
  lists[s * A_ + pos] = a;
}

// ---------------------------------------------------------------------------
// logits[a,p] = sum_e relu(att1[s,p,e] + att2[a,e]) * w_fc[e]
// Block = (scene, 64-px chunk); lane = (px = tid>>2, eq = tid&3).
// Each lane owns e in [16*eq, 16*eq+16): a1/wf/t are 16 regs each ->
// low VGPR -> 4-8 waves/SIMD. Per agent: 4 batched LDS b128 reads,
// 4 independent fma chains, 2 shfl_xor for the 4-lane e-reduce.
// ---------------------------------------------------------------------------
__global__ __launch_bounds__(256) void logits_kernel(
    const float* __restrict__ gs, const float* __restrict__ Wsn,
    const float* __restrict__ bsn, const float* __restrict__ wfc,
    const float* __restrict__ att2, const int* __restrict__ counts,
    const int* __restrict__ lists, float* __restrict__ logits) {
  const int s   = blockIdx.x >> 5;
  const int p0  = (blockIdx.x & (NLCH - 1)) * LPX;
  const int tid = threadIdx.x;
  const int px  = tid >> 2;          // 0..63
  const int eq  = tid & 3;           // e-quarter

  __shared__ float  gsl[LPX][33];    // padded: conflict-free px-major reads
  __shared__ float4 Wl4[32 * 16];    // W_sn [c][e4]
  __shared__ float4 a2l[32][16];     // att2 rows of current agent group
  __shared__ int    aidl[32];

  // stage W_sn (512 float4)
  const float4* W4 = (const float4*)Wsn;
  Wl4[tid]       = W4[tid];
  Wl4[tid + 256] = W4[tid + 256];

  // stage gs chunk: 64 px x 32 c = 512 float4
  const float4* g4 = (const float4*)(gs + ((long)s * P_ + p0) * C_);
#pragma unroll
  for (int k = 0; k < 2; ++k) {
    const int f = tid + k * 256;
    const float4 v = g4[f];
    const int pp = f >> 3, c0 = (f & 7) * 4;
    gsl[pp][c0]     = v.x;
    gsl[pp][c0 + 1] = v.y;
    gsl[pp][c0 + 2] = v.z;
    gsl[pp][c0 + 3] = v.w;
  }

  // per-lane w_fc quads and bias-initialized att1 accumulator
  const float4* wf4 = (const float4*)wfc;
  const float4* b4  = (const float4*)bsn;
  float4 wf[4], a1[4];
#pragma unroll
  for (int q = 0; q < 4; ++q) { wf[q] = wf4[eq * 4 + q]; a1[q] = b4[eq * 4 + q]; }
  __syncthreads();

  // att1 for (pixel px, e-range of this lane): 32c x 16e fma
#pragma unroll
  for (int c = 0; c < 32; ++c) {
    const float g = gsl[px][c];
#pragma unroll
    for (int q = 0; q < 4; ++q) {
      const float4 w = Wl4[c * 16 + eq * 4 + q];
      a1[q].x = fmaf(g, w.x, a1[q].x);
      a1[q].y = fmaf(g, w.y, a1[q].y);
      a1[q].z = fmaf(g, w.z, a1[q].z);
      a1[q].w = fmaf(g, w.w, a1[q].w);
    }
  }

  const int n_s = counts[s];
  for (int g0 = 0; g0 < n_s; g0 += 32) {
    const int m = min(32, n_s - g0);
    __syncthreads();                    // prev group's a2l reads done
    if (tid < m) aidl[tid] = lists[s * A_ + g0 + tid];
    __syncthreads();
#pragma unroll
    for (int k = 0; k < 2; ++k) {
      const int idx = tid + k * 256;    // 0..511
      const int j = idx >> 4, e4 = idx & 15;
      if (j < m) a2l[j][e4] = ((const float4*)att2)[aidl[j] * 16 + e4];
    }
    __syncthreads();

    for (int j = 0; j < m; ++j) {
      const float4 t0 = a2l[j][eq * 4 + 0];
      const float4 t1 = a2l[j][eq * 4 + 1];
      const float4 t2 = a2l[j][eq * 4 + 2];
      const float4 t3 = a2l[j][eq * 4 + 3];
      float c0 = 0.f, c1 = 0.f, c2 = 0.f, c3 = 0.f;
      c0 = fmaf(fmaxf(a1[0].x + t0.x, 0.f), wf[0].x, c0);
      c1 = fmaf(fmaxf(a1[0].y + t0.y, 0.f), wf[0].y, c1);
      c2 = fmaf(fmaxf(a1[0].z + t0.z, 0.f), wf[0].z, c2);
      c3 = fmaf(fmaxf(a1[0].w + t0.w, 0.f), wf[0].w, c3);
      c0 = fmaf(fmaxf(a1[1].x + t1.x, 0.f), wf[1].x, c0);
      c1 = fmaf(fmaxf(a1[1].y + t1.y, 0.f), wf[1].y, c1);
      c2 = fmaf(fmaxf(a1[1].z + t1.z, 0.f), wf[1].z, c2);
      c3 = fmaf(fmaxf(a1[1].w + t1.w, 0.f), wf[1].w, c3);
      c0 = fmaf(fmaxf(a1[2].x + t2.x, 0.f), wf[2].x, c0);
      c1 = fmaf(fmaxf(a1[2].y + t2.y, 0.f), wf[2].y, c1);
      c2 = fmaf(fmaxf(a1[2].z + t2.z, 0.f), wf[2].z, c2);
      c3 = fmaf(fmaxf(a1[2].w + t2.w, 0.f), wf[2].w, c3);
      c0 = fmaf(fmaxf(a1[3].x + t3.x, 0.f), wf[3].x, c0);
      c1 = fmaf(fmaxf(a1[3].y + t3.y, 0.f), wf[3].y, c1);
      c2 = fmaf(fmaxf(a1[3].z + t3.z, 0.f), wf[3].z, c2);
      c3 = fmaf(fmaxf(a1[3].w + t3.w, 0.f), wf[3].w, c3);
      float r = (c0 + c1) + (c2 + c3);
      r += __shfl_xor(r, 1);
      r += __shfl_xor(r, 2);
      if (eq == 0) logits[(long)aidl[j] * P_ + p0 + px] = r;
    }
  }
}

// ---------------------------------------------------------------------------
// Per-agent softmax stats: stats[a] = (max, 1/sum(exp(l-max)))
// ---------------------------------------------------------------------------
__global__ __launch_bounds__(256) void stats_kernel(
    const float* __restrict__ logits, float2* __restrict__ stats) {
  const int a = blockIdx.x, tid = threadIdx.x;
  __shared__ float red[8];
  const float4* l4 = (const float4*)(logits + (long)a * P_);
  const float4 v0 = l4[tid], v1 = l4[tid + 256];
  float m = fmaxf(fmaxf(fmaxf(v0.x, v0.y), fmaxf(v0.z, v0.w)),
                  fmaxf(fmaxf(v1.x, v1.y), fmaxf(v1.z, v1.w)));
#pragma unroll
  for (int off = 1; off < 64; off <<= 1) m = fmaxf(m, __shfl_xor(m, off));
  if ((tid & 63) == 0) red[tid >> 6] = m;
  __syncthreads();
  m = fmaxf(fmaxf(red[0], red[1]), fmaxf(red[2], red[3]));

  float sum = __expf(v0.x - m) + __expf(v0.y - m) + __expf(v0.z - m) + __expf(v0.w - m)
            + __expf(v1.x - m) + __expf(v1.y - m) + __expf(v1.z - m) + __expf(v1.w - m);
#pragma unroll
  for (int off = 1; off < 64; off <<= 1) sum += __shfl_xor(sum, off);
  if ((tid & 63) == 0) red[4 + (tid >> 6)] = sum;
  __syncthreads();
  if (tid == 0) {
    const float Z = red[4] + red[5] + red[6] + red[7];
    stats[a] = make_float2(m, 1.0f / Z);
  }
}

// ---------------------------------------------------------------------------
// out[a,c] += sum_{p in chunk} alpha[a,p] * gs[s,p,c]
// Block = (scene, 128-px chunk). alpha rows padded to 132 floats (528 B)
// to kill the 8-way bank conflict of the 512 B power-of-2 stride.
// float4 alpha reads + 4 independent acc chains.
// ---------------------------------------------------------------------------
__global__ __launch_bounds__(256) void pool_kernel(
    const float* __restrict__ logits, const float2* __restrict__ stats,
    const int* __restrict__ counts, const int* __restrict__ lists,
    const float* __restrict__ gs, float* __restrict__ out) {
  const int s   = blockIdx.x >> 4;
  const int p0  = (blockIdx.x & (NPCH - 1)) * PPC;
  const int tid = threadIdx.x;
  const int j   = tid >> 3;              // agent slot 0..31
  const int c4  = tid & 7;               // channel quad

  __shared__ float4 gsl[PPC][8];         // 16 KB
  __shared__ float  alpha_l[32][132];    // 16.9 KB, padded stride
  __shared__ float2 sm[32];
  __shared__ int    aid[32];

  const float4* g4 = (const float4*)(gs + ((long)s * P_ + p0) * C_);
  float4* gl = (float4*)gsl;
#pragma unroll
  for (int k = 0; k < 4; ++k) gl[tid + k * 256] = g4[tid + k * 256];

  const float4* l4 = (const float4*)logits;
  const int n_s = counts[s];

  for (int g0 = 0; g0 < n_s; g0 += 32) {
    const int m = min(32, n_s - g0);
    __syncthreads();                     // prev-group LDS reads done (+gsl ready)
    if (tid < m) {
      const int a = lists[s * A_ + g0 + tid];
      aid[tid] = a;
      sm[tid]  = stats[a];
    }
    __syncthreads();

    // stage alpha: 32 agents x 128 px = 1024 float4
#pragma unroll
    for (int k = 0; k < 4; ++k) {
      const int idx = tid + k * 256;     // 0..1023
      const int jj = idx >> 5, p4 = idx & 31;
      if (jj < m) {
        const float2 ms = sm[jj];
        const float4 v  = l4[(long)aid[jj] * (P_ / 4) + (p0 >> 2) + p4];
        float4 al;
        al.x = __expf(v.x - ms.x) * ms.y;
        al.y = __expf(v.y - ms.x) * ms.y;
        al.z = __expf(v.z - ms.x) * ms.y;
        al.w = __expf(v.w - ms.x) * ms.y;
        ((float4*)&alpha_l[jj][0])[p4] = al;
      }
    }
    __syncthreads();

    if (j < m) {
      float4 a0 = make_float4(0.f, 0.f, 0.f, 0.f);
      float4 a1 = make_float4(0.f, 0.f, 0.f, 0.f);
      float4 a2 = make_float4(0.f, 0.f, 0.f, 0.f);
      float4 a3 = make_float4(0.f, 0.f, 0.f, 0.f);
#pragma unroll 4
      for (int p4 = 0; p4 < PPC / 4; ++p4) {
        const float4 aw = ((const float4*)&alpha_l[j][0])[p4];
        const float4 v0 = gsl[p4 * 4 + 0][c4];
        const float4 v1 = gsl[p4 * 4 + 1][c4];
        const float4 v2 = gsl[p4 * 4 + 2][c4];
        const float4 v3 = gsl[p4 * 4 + 3][c4];
        a0.x = fmaf(aw.x, v0.x, a0.x); a0.y = fmaf(aw.x, v0.y, a0.y);
        a0.z = fmaf(aw.x, v0.z, a0.z); a0.w = fmaf(aw.x, v0.w, a0.w);
        a1.x = fmaf(aw.y, v1.x, a1.x); a1.y = fmaf(aw.y, v1.y, a1.y);
        a1.z = fmaf(aw.y, v1.z, a1.z); a1.w = fmaf(aw.y, v1.w, a1.w);
        a2.x = fmaf(aw.z, v2.x, a2.x); a2.y = fmaf(aw.z, v2.y, a2.y);
        a2.z = fmaf(aw.z, v2.z, a2.z); a2.w = fmaf(aw.z, v2.w, a2.w);
        a3.x = fmaf(aw.w, v3.x, a3.x); a3.y = fmaf(aw.w, v3.y, a3.y);
        a3.z = fmaf(aw.w, v3.z, a3.z); a3.w = fmaf(aw.w, v3.w, a3.w);
      }
      const float4 acc = make_float4((a0.x + a1.x) + (a2.x + a3.x),
                                     (a0.y + a1.y) + (a2.y + a3.y),
                                     (a0.z + a1.z) + (a2.z + a3.z),
                                     (a0.w + a1.w) + (a2.w + a3.w));
      float* op = out + (long)aid[j] * C_ + c4 * 4;
      atomicAdd(op,     acc.x);
      atomicAdd(op + 1, acc.y);
      atomicAdd(op + 2, acc.z);
      atomicAdd(op + 3, acc.w);
    }
  }
}

// ---------------------------------------------------------------------------
extern "C" void kernel_launch(void* const* d_in, const int* in_sizes, int n_in,
                              void* d_out, int out_size, void* d_ws, size_t ws_size,
                              hipStream_t stream) {
  const float* gs   = (const float*)d_in[0];  // [S,P,C]
  const int*   sidx = (const int*)  d_in[1];  // [A]
  const float* de   = (const float*)d_in[2];  // [A,D]
  const float* Wsn  = (const float*)d_in[3];  // [C,E]
  const float* bsn  = (const float*)d_in[4];  // [E]
  const float* Wdf  = (const float*)d_in[5];  // [D,E]
  const float* bdf  = (const float*)d_in[6];  // [E]
  const float* wfc  = (const float*)d_in[7];  // [E]
  // d_in[8] = b_fc: constant shift, softmax-invariant — unused.
  float* out = (float*)d_out;

  float*  att2   = (float*)d_ws;                       // A*E   = 0.5 MB
  float*  logits = att2 + (long)A_ * E_;               // A*P   = 16 MB
  float2* stats  = (float2*)(logits + (long)A_ * P_);  // A     = 16 KB
  int*    counts = (int*)(stats + A_);                 // 64
  int*    lists  = counts + 64;                        // S*A   = 0.5 MB

  hipMemsetAsync(counts, 0, 64 * sizeof(int), stream);
  hipMemsetAsync(out, 0, (size_t)out_size * sizeof(float), stream);

  att2_kernel   <<<A_ / 16,    256, 0, stream>>>(de, Wdf, bdf, att2);
  scatter_kernel<<<A_ / 256,   256, 0, stream>>>(sidx, counts, lists);
  logits_kernel <<<S_ * NLCH,  256, 0, stream>>>(gs, Wsn, bsn, wfc, att2,
                                                 counts, lists, logits);
  stats_kernel  <<<A_,         256, 0, stream>>>(logits, stats);
  pool_kernel   <<<S_ * NPCH,  256, 0, stream>>>(logits, stats, counts,
                                                 lists, gs, out);
}